// Round 12
// baseline (2255.124 us; speedup 1.0000x reference)
//
#include <hip/hip_runtime.h>
#include <stdint.h>

// MyVanillaRNN: B=64, T=512, INPUT=512, HIDDEN=1024
// out = concat( pre[B,T,H] (f32), h_final[B,H] (f32) )

typedef __attribute__((ext_vector_type(8))) short bf16x8;
typedef __attribute__((ext_vector_type(4))) float f32x4;

__device__ __forceinline__ uint32_t f2bf(float f) {
    union { float f; uint32_t u; } v; v.f = f;
    return (v.u + 0x7FFFu + ((v.u >> 16) & 1u)) >> 16;   // RNE
}
__device__ __forceinline__ uint32_t pack2bf(float a, float b) {
    return f2bf(a) | (f2bf(b) << 16);
}
__device__ __forceinline__ float fast_tanh(float x) {
    const float xc = fminf(fmaxf(x, -15.f), 15.f);
    const float e  = __expf(2.f * xc);
    return (e - 1.f) * __builtin_amdgcn_rcpf(e + 1.f);
}

// ---------------------------------------------------------------------------
// Phase 1: out[m][n] = sum_k x[m][k]*Wx[n][k] + bx[n] + bh[n]
// M=32768, N=1024, K=512.  128x128 tile, BK=64, 4 waves, bf16 MFMA.
// ---------------------------------------------------------------------------
__global__ __launch_bounds__(256) void xproj_gemm(
    const float* __restrict__ x, const float* __restrict__ Wx,
    const float* __restrict__ bx, const float* __restrict__ bh,
    float* __restrict__ out)
{
    __shared__ __align__(16) uint8_t Ab[128 * 128];
    __shared__ __align__(16) uint8_t Bb[128 * 128];

    const int tid  = threadIdx.x;
    const int lane = tid & 63;
    const int wid  = tid >> 6;
    const int wm = wid >> 1, wn = wid & 1;
    const int m0 = (int)(blockIdx.x >> 3) * 128;
    const int n0 = (int)(blockIdx.x & 7) * 128;

    f32x4 acc[4][4];
    #pragma unroll
    for (int i = 0; i < 4; ++i)
        #pragma unroll
        for (int j = 0; j < 4; ++j) acc[i][j] = (f32x4){0.f, 0.f, 0.f, 0.f};

    const int sr = tid >> 4;
    const int sk = (tid & 15) << 2;

    for (int k0 = 0; k0 < 512; k0 += 64) {
        __syncthreads();
        #pragma unroll
        for (int p = 0; p < 8; ++p) {
            const int r = sr + p * 16;
            const float4 a = *(const float4*)(x  + (size_t)(m0 + r) * 512 + k0 + sk);
            const float4 b = *(const float4*)(Wx + (size_t)(n0 + r) * 512 + k0 + sk);
            const int byo = r * 128 + ((sk << 1) ^ ((r & 7) << 4));
            *(uint2*)(Ab + byo) = make_uint2(pack2bf(a.x, a.y), pack2bf(a.z, a.w));
            *(uint2*)(Bb + byo) = make_uint2(pack2bf(b.x, b.y), pack2bf(b.z, b.w));
        }
        __syncthreads();
        #pragma unroll
        for (int kt = 0; kt < 2; ++kt) {
            bf16x8 af[4], bfr[4];
            const int kb = (kt << 6) + ((lane >> 4) << 4);
            #pragma unroll
            for (int q = 0; q < 4; ++q) {
                const int ar = wm * 64 + q * 16 + (lane & 15);
                const int br = wn * 64 + q * 16 + (lane & 15);
                af[q]  = *(const bf16x8*)(Ab + ar * 128 + (kb ^ ((ar & 7) << 4)));
                bfr[q] = *(const bf16x8*)(Bb + br * 128 + (kb ^ ((br & 7) << 4)));
            }
            #pragma unroll
            for (int mt = 0; mt < 4; ++mt)
                #pragma unroll
                for (int nt = 0; nt < 4; ++nt)
                    acc[mt][nt] = __builtin_amdgcn_mfma_f32_16x16x32_bf16(
                        af[mt], bfr[nt], acc[mt][nt], 0, 0, 0);
        }
    }

    #pragma unroll
    for (int nt = 0; nt < 4; ++nt) {
        const int n = n0 + wn * 64 + nt * 16 + (lane & 15);
        const float bias = bx[n] + bh[n];
        #pragma unroll
        for (int mt = 0; mt < 4; ++mt) {
            const int mb = m0 + wm * 64 + mt * 16 + ((lane >> 4) << 2);
            #pragma unroll
            for (int i = 0; i < 4; ++i)
                out[(size_t)(mb + i) * 1024 + n] = acc[mt][nt][i] + bias;
        }
    }
}

// ---------------------------------------------------------------------------
// Phase 2: persistent scan. 8 groups (8 batches) x 8 blocks (128 H-cols).
// EXACT round-11 structure (best verified: 1443us) with ONE change:
//   PIPELINED A/B poll in plain C: issue set B, check set A, issue set A,
//   check set B. The compiler tracks loads individually and waits only the
//   older set (vmcnt(14)) before each check -> checks spaced ~RT/2 and the
//   check of one set overlaps the other's flight. (r10's asm version was
//   compiler-unsafe; r8's was confounded by u64 flat loads + per-wave
//   restructure. This is the minimal, safe form.)
// h exchange: tagged words (bf16(h)<<16 | (t+1)); relaxed agent-scope
// atomics only (rounds 3/5/7: L2-local paths never deliver fresh data).
// htile row stride 2064B (bank-optimal for the MFMA b128 reads).
// Own 128 cols never cross global (parity double-buffered LDS tile).
// xp software-pipelined one step ahead. LDS padded >80KB -> 1 block/CU.
// ---------------------------------------------------------------------------
__global__ __launch_bounds__(512, 1) void rnn_scan(
    const float* __restrict__ h0, const float* __restrict__ Wh,
    float* __restrict__ out, float* __restrict__ hfin,
    uint32_t* __restrict__ hbuf)   // [2][64][1024] tagged words
{
    // rows 0..7 (x2064B) per parity used; rest pads LDS > 80KB => 1 block/CU.
    __shared__ __align__(16) uint8_t htile[2][49152];

    const int tid  = threadIdx.x;
    const int lane = tid & 63;
    const int wid  = tid >> 6;          // 0..7
    const int g    = (int)blockIdx.x & 7;
    const int nb   = (int)blockIdx.x >> 3;
    const int gb0  = g * 8;             // batch base
    const int col  = nb * 128 + wid * 16 + (lane & 15);   // own output col
    const int r4b  = ((lane >> 4) & 1) << 2;              // 0/4 batch sub-base

    // --- Wh B-fragments: own col, full K. frag kt elem j <-> k=kt*32+(lane>>4)*8+j
    bf16x8 whf[32];
    {
        const float* wp = Wh + (size_t)col * 1024 + ((lane >> 4) << 3);
        #pragma unroll
        for (int kt = 0; kt < 32; ++kt) {
            const float4 w0 = *(const float4*)(wp + kt * 32);
            const float4 w1 = *(const float4*)(wp + kt * 32 + 4);
            bf16x8 f;
            f[0] = (short)f2bf(w0.x); f[1] = (short)f2bf(w0.y);
            f[2] = (short)f2bf(w0.z); f[3] = (short)f2bf(w0.w);
            f[4] = (short)f2bf(w1.x); f[5] = (short)f2bf(w1.y);
            f[6] = (short)f2bf(w1.z); f[7] = (short)f2bf(w1.w);
            whf[kt] = f;
        }
    }

    // --- init: publish own slice of h0 (tag 1, parity 0) + own LDS fill
    {
        const int colI = nb * 128 + lane * 2;   // two adjacent own cols
        const uint32_t u0 = f2bf(h0[(size_t)(gb0 + wid) * 1024 + colI]);
        const uint32_t u1 = f2bf(h0[(size_t)(gb0 + wid) * 1024 + colI + 1]);
        const int idx = (gb0 + wid) * 1024 + colI;
        __hip_atomic_store(&hbuf[idx],     (u0 << 16) | 1u, __ATOMIC_RELAXED, __HIP_MEMORY_SCOPE_AGENT);
        __hip_atomic_store(&hbuf[idx + 1], (u1 << 16) | 1u, __ATOMIC_RELAXED, __HIP_MEMORY_SCOPE_AGENT);
        *(uint32_t*)(htile[0] + wid * 2064 + colI * 2) = u0 | (u1 << 16);
    }

    // --- poll indices: 7 remote blocks x 2 words; batch row = wid
    const int pb  = wid;
    const int pc0 = lane * 2;
    int ridx[7];
    #pragma unroll
    for (int r = 0; r < 7; ++r) {
        const int rbk = (nb + 1 + r) & 7;
        ridx[r] = (gb0 + pb) * 1024 + rbk * 128 + pc0;
    }

    // --- xp preload for t=0 (all lanes; lanes>=32 mirror lanes<32)
    float xpv[4];
    #pragma unroll
    for (int i = 0; i < 4; ++i)
        xpv[i] = out[((size_t)(gb0 + r4b + i) * 512 + 0) * 1024 + col];

    for (int t = 0; t < 512; ++t) {
        const int cur = t & 1;
        uint32_t* const src = hbuf + cur * 65536;
        uint32_t* const dst = hbuf + (cur ^ 1) * 65536;
        const uint32_t exptag = (uint32_t)(t + 1);
        const uint32_t ntag   = exptag + 1;

        // --- phase A: PIPELINED A/B poll of the 7 remote slices.
        // Issue one set before checking the other: compiler waits only the
        // older set's loads (partial vmcnt), so checks overlap flight time.
        uint32_t v[14];
        {
            uint32_t va[14], vb[14];
            #pragma unroll
            for (int r = 0; r < 7; ++r) {
                va[2 * r]     = __hip_atomic_load(&src[ridx[r]],     __ATOMIC_RELAXED, __HIP_MEMORY_SCOPE_AGENT);
                va[2 * r + 1] = __hip_atomic_load(&src[ridx[r] + 1], __ATOMIC_RELAXED, __HIP_MEMORY_SCOPE_AGENT);
            }
            int rounds = 0;
            while (true) {
                #pragma unroll
                for (int r = 0; r < 7; ++r) {
                    vb[2 * r]     = __hip_atomic_load(&src[ridx[r]],     __ATOMIC_RELAXED, __HIP_MEMORY_SCOPE_AGENT);
                    vb[2 * r + 1] = __hip_atomic_load(&src[ridx[r] + 1], __ATOMIC_RELAXED, __HIP_MEMORY_SCOPE_AGENT);
                }
                bool ok = true;
                #pragma unroll
                for (int p = 0; p < 14; ++p) ok &= ((va[p] & 0xFFFFu) == exptag);
                if (ok) {
                    #pragma unroll
                    for (int p = 0; p < 14; ++p) v[p] = va[p];
                    break;
                }
                #pragma unroll
                for (int r = 0; r < 7; ++r) {
                    va[2 * r]     = __hip_atomic_load(&src[ridx[r]],     __ATOMIC_RELAXED, __HIP_MEMORY_SCOPE_AGENT);
                    va[2 * r + 1] = __hip_atomic_load(&src[ridx[r] + 1], __ATOMIC_RELAXED, __HIP_MEMORY_SCOPE_AGENT);
                }
                ok = true;
                #pragma unroll
                for (int p = 0; p < 14; ++p) ok &= ((vb[p] & 0xFFFFu) == exptag);
                if (ok) {
                    #pragma unroll
                    for (int p = 0; p < 14; ++p) v[p] = vb[p];
                    break;
                }
                if (++rounds > 256) __builtin_amdgcn_s_sleep(2);   // paranoia only
            }
        }
        // stage remote h into this parity's LDS tile (stride-2064 rows)
        #pragma unroll
        for (int r = 0; r < 7; ++r) {
            const int rbk = (nb + 1 + r) & 7;
            const int c0  = rbk * 128 + pc0;
            const uint32_t pk = (v[2 * r] >> 16) | (v[2 * r + 1] & 0xFFFF0000u);
            *(uint32_t*)(htile[cur] + pb * 2064 + c0 * 2) = pk;
        }
        __syncthreads();   // htile[cur] complete (remote staged + own from t-1)

        // --- xp prefetch for NEXT step (off the poll's critical path)
        float xnext[4];
        if (t < 511) {
            #pragma unroll
            for (int i = 0; i < 4; ++i)
                xnext[i] = out[((size_t)(gb0 + r4b + i) * 512 + (t + 1)) * 1024 + col];
        }

        // --- phase B: acc = h . Wh[col]^T over full K, 4 interleaved chains
        f32x4 a0 = (f32x4){0.f,0.f,0.f,0.f}, a1 = a0, a2 = a0, a3 = a0;
        {
            const int b_  = lane & 7;
            const int kbx = (lane >> 4) << 4;
            const uint8_t* hb = htile[cur] + b_ * 2064;
            #pragma unroll
            for (int kt = 0; kt < 32; kt += 4) {
                const bf16x8 f0 = *(const bf16x8*)(hb + (kt    ) * 64 + kbx);
                const bf16x8 f1 = *(const bf16x8*)(hb + (kt + 1) * 64 + kbx);
                const bf16x8 f2 = *(const bf16x8*)(hb + (kt + 2) * 64 + kbx);
                const bf16x8 f3 = *(const bf16x8*)(hb + (kt + 3) * 64 + kbx);
                a0 = __builtin_amdgcn_mfma_f32_16x16x32_bf16(f0, whf[kt    ], a0, 0, 0, 0);
                a1 = __builtin_amdgcn_mfma_f32_16x16x32_bf16(f1, whf[kt + 1], a1, 0, 0, 0);
                a2 = __builtin_amdgcn_mfma_f32_16x16x32_bf16(f2, whf[kt + 2], a2, 0, 0, 0);
                a3 = __builtin_amdgcn_mfma_f32_16x16x32_bf16(f3, whf[kt + 3], a3, 0, 0, 0);
            }
        }

        // --- phase C: lanes<32 publish h (critical path); lanes>=32 (which
        // hold a duplicate C fragment) write out[] concurrently.
        float pre[4], hn[4];
        #pragma unroll
        for (int i = 0; i < 4; ++i) {
            pre[i] = ((a0[i] + a1[i]) + (a2[i] + a3[i])) + xpv[i];
            hn[i]  = fast_tanh(pre[i]);
        }
        if (lane < 32) {
            if (t < 511) {
                uint32_t hu[4];
                #pragma unroll
                for (int i = 0; i < 4; ++i) hu[i] = f2bf(hn[i]);
                #pragma unroll
                for (int i = 0; i < 4; ++i)
                    __hip_atomic_store(&dst[(gb0 + r4b + i) * 1024 + col], (hu[i] << 16) | ntag,
                                       __ATOMIC_RELAXED, __HIP_MEMORY_SCOPE_AGENT);
                // own slice -> next parity's LDS tile (never crosses global)
                #pragma unroll
                for (int i = 0; i < 4; ++i)
                    *(uint16_t*)(htile[cur ^ 1] + (r4b + i) * 2064 + col * 2) = (uint16_t)hu[i];
            }
        } else {
            #pragma unroll
            for (int i = 0; i < 4; ++i) {
                out[((size_t)(gb0 + r4b + i) * 512 + t) * 1024 + col] = pre[i];
                if (t == 511) hfin[(size_t)(gb0 + r4b + i) * 1024 + col] = hn[i];
            }
        }
        #pragma unroll
        for (int i = 0; i < 4; ++i) xpv[i] = xnext[i];
    }
}

// ---------------------------------------------------------------------------
extern "C" void kernel_launch(void* const* d_in, const int* in_sizes, int n_in,
                              void* d_out, int out_size, void* d_ws, size_t ws_size,
                              hipStream_t stream) {
    const float* x   = (const float*)d_in[0];   // [64,512,512]
    const float* h0_ = (const float*)d_in[1];   // [64,1024]
    const float* Wx  = (const float*)d_in[2];   // [1024,512]
    const float* bx  = (const float*)d_in[3];   // [1024]
    const float* Wh  = (const float*)d_in[4];   // [1024,1024]
    const float* bh  = (const float*)d_in[5];   // [1024]
    float* out  = (float*)d_out;                         // [64,512,1024] pre
    float* hfin = out + (size_t)64 * 512 * 1024;         // [64,1024]
    uint32_t* hbuf = (uint32_t*)d_ws;                    // [2][64][1024] u32 = 512 KB

    // invalidate all tags (0xFFFF matches no step tag 1..513)
    hipMemsetAsync(d_ws, 0xFF, (size_t)2 * 64 * 1024 * sizeof(uint32_t), stream);

    xproj_gemm<<<dim3(2048), dim3(256), 0, stream>>>(x, Wx, bx, bh, out);
    rnn_scan<<<dim3(64), dim3(512), 0, stream>>>(h0_, Wh, out, hfin, hbuf);
}

// Round 13
// 1943.666 us; speedup vs baseline: 1.1602x; 1.1602x over previous
//
#include <hip/hip_runtime.h>
#include <stdint.h>

// MyVanillaRNN: B=64, T=512, INPUT=512, HIDDEN=1024
// out = concat( pre[B,T,H] (f32), h_final[B,H] (f32) )

typedef __attribute__((ext_vector_type(8))) short bf16x8;
typedef __attribute__((ext_vector_type(4))) float f32x4;

__device__ __forceinline__ uint32_t f2bf(float f) {
    union { float f; uint32_t u; } v; v.f = f;
    return (v.u + 0x7FFFu + ((v.u >> 16) & 1u)) >> 16;   // RNE
}
__device__ __forceinline__ uint32_t pack2bf(float a, float b) {
    return f2bf(a) | (f2bf(b) << 16);
}
__device__ __forceinline__ float fast_tanh(float x) {
    const float xc = fminf(fmaxf(x, -15.f), 15.f);
    const float e  = __expf(2.f * xc);
    return (e - 1.f) * __builtin_amdgcn_rcpf(e + 1.f);
}

// ---------------------------------------------------------------------------
// Phase 1: out[m][n] = sum_k x[m][k]*Wx[n][k] + bx[n] + bh[n]
// M=32768, N=1024, K=512.  128x128 tile, BK=64, 4 waves, bf16 MFMA.
// ---------------------------------------------------------------------------
__global__ __launch_bounds__(256) void xproj_gemm(
    const float* __restrict__ x, const float* __restrict__ Wx,
    const float* __restrict__ bx, const float* __restrict__ bh,
    float* __restrict__ out)
{
    __shared__ __align__(16) uint8_t Ab[128 * 128];
    __shared__ __align__(16) uint8_t Bb[128 * 128];

    const int tid  = threadIdx.x;
    const int lane = tid & 63;
    const int wid  = tid >> 6;
    const int wm = wid >> 1, wn = wid & 1;
    const int m0 = (int)(blockIdx.x >> 3) * 128;
    const int n0 = (int)(blockIdx.x & 7) * 128;

    f32x4 acc[4][4];
    #pragma unroll
    for (int i = 0; i < 4; ++i)
        #pragma unroll
        for (int j = 0; j < 4; ++j) acc[i][j] = (f32x4){0.f, 0.f, 0.f, 0.f};

    const int sr = tid >> 4;
    const int sk = (tid & 15) << 2;

    for (int k0 = 0; k0 < 512; k0 += 64) {
        __syncthreads();
        #pragma unroll
        for (int p = 0; p < 8; ++p) {
            const int r = sr + p * 16;
            const float4 a = *(const float4*)(x  + (size_t)(m0 + r) * 512 + k0 + sk);
            const float4 b = *(const float4*)(Wx + (size_t)(n0 + r) * 512 + k0 + sk);
            const int byo = r * 128 + ((sk << 1) ^ ((r & 7) << 4));
            *(uint2*)(Ab + byo) = make_uint2(pack2bf(a.x, a.y), pack2bf(a.z, a.w));
            *(uint2*)(Bb + byo) = make_uint2(pack2bf(b.x, b.y), pack2bf(b.z, b.w));
        }
        __syncthreads();
        #pragma unroll
        for (int kt = 0; kt < 2; ++kt) {
            bf16x8 af[4], bfr[4];
            const int kb = (kt << 6) + ((lane >> 4) << 4);
            #pragma unroll
            for (int q = 0; q < 4; ++q) {
                const int ar = wm * 64 + q * 16 + (lane & 15);
                const int br = wn * 64 + q * 16 + (lane & 15);
                af[q]  = *(const bf16x8*)(Ab + ar * 128 + (kb ^ ((ar & 7) << 4)));
                bfr[q] = *(const bf16x8*)(Bb + br * 128 + (kb ^ ((br & 7) << 4)));
            }
            #pragma unroll
            for (int mt = 0; mt < 4; ++mt)
                #pragma unroll
                for (int nt = 0; nt < 4; ++nt)
                    acc[mt][nt] = __builtin_amdgcn_mfma_f32_16x16x32_bf16(
                        af[mt], bfr[nt], acc[mt][nt], 0, 0, 0);
        }
    }

    #pragma unroll
    for (int nt = 0; nt < 4; ++nt) {
        const int n = n0 + wn * 64 + nt * 16 + (lane & 15);
        const float bias = bx[n] + bh[n];
        #pragma unroll
        for (int mt = 0; mt < 4; ++mt) {
            const int mb = m0 + wm * 64 + mt * 16 + ((lane >> 4) << 2);
            #pragma unroll
            for (int i = 0; i < 4; ++i)
                out[(size_t)(mb + i) * 1024 + n] = acc[mt][nt][i] + bias;
        }
    }
}

// ---------------------------------------------------------------------------
// Phase 2: persistent scan. 8 groups (8 batches) x 8 blocks (128 H-cols).
// EXACT round-11 structure (best verified: 1443us) with ONE change:
//   MASKED SELECTIVE RE-POLL: retry rounds reload ONLY the words whose tag
//   still mismatches (parallel predicated loads under exec-mask, then one
//   check -- NOT round-1's serial per-word spin). Evidence r8/r12: the
//   detect phase is congestion-bound at the memory-side coherence point --
//   more poll requests = slower. This cuts round-2+ traffic ~10x.
// h exchange: tagged words (bf16(h)<<16 | (t+1)); relaxed agent-scope
// atomics only (r3/5/7: L2-local paths never deliver fresh data; r9:
// ACK+tag 2-hop serializes; r10: asm streaming poll compiler-unsafe;
// r12: pipelined A/B poll doubles traffic and congests).
// htile row stride 2064B. Own cols never cross global (parity LDS dbuf).
// xp software-pipelined one step ahead. LDS padded >80KB -> 1 block/CU.
// ---------------------------------------------------------------------------
__global__ __launch_bounds__(512, 1) void rnn_scan(
    const float* __restrict__ h0, const float* __restrict__ Wh,
    float* __restrict__ out, float* __restrict__ hfin,
    uint32_t* __restrict__ hbuf)   // [2][64][1024] tagged words
{
    // rows 0..7 (x2064B) per parity used; rest pads LDS > 80KB => 1 block/CU.
    __shared__ __align__(16) uint8_t htile[2][49152];

    const int tid  = threadIdx.x;
    const int lane = tid & 63;
    const int wid  = tid >> 6;          // 0..7
    const int g    = (int)blockIdx.x & 7;
    const int nb   = (int)blockIdx.x >> 3;
    const int gb0  = g * 8;             // batch base
    const int col  = nb * 128 + wid * 16 + (lane & 15);   // own output col
    const int r4b  = ((lane >> 4) & 1) << 2;              // 0/4 batch sub-base

    // --- Wh B-fragments: own col, full K. frag kt elem j <-> k=kt*32+(lane>>4)*8+j
    bf16x8 whf[32];
    {
        const float* wp = Wh + (size_t)col * 1024 + ((lane >> 4) << 3);
        #pragma unroll
        for (int kt = 0; kt < 32; ++kt) {
            const float4 w0 = *(const float4*)(wp + kt * 32);
            const float4 w1 = *(const float4*)(wp + kt * 32 + 4);
            bf16x8 f;
            f[0] = (short)f2bf(w0.x); f[1] = (short)f2bf(w0.y);
            f[2] = (short)f2bf(w0.z); f[3] = (short)f2bf(w0.w);
            f[4] = (short)f2bf(w1.x); f[5] = (short)f2bf(w1.y);
            f[6] = (short)f2bf(w1.z); f[7] = (short)f2bf(w1.w);
            whf[kt] = f;
        }
    }

    // --- init: publish own slice of h0 (tag 1, parity 0) + own LDS fill
    {
        const int colI = nb * 128 + lane * 2;   // two adjacent own cols
        const uint32_t u0 = f2bf(h0[(size_t)(gb0 + wid) * 1024 + colI]);
        const uint32_t u1 = f2bf(h0[(size_t)(gb0 + wid) * 1024 + colI + 1]);
        const int idx = (gb0 + wid) * 1024 + colI;
        __hip_atomic_store(&hbuf[idx],     (u0 << 16) | 1u, __ATOMIC_RELAXED, __HIP_MEMORY_SCOPE_AGENT);
        __hip_atomic_store(&hbuf[idx + 1], (u1 << 16) | 1u, __ATOMIC_RELAXED, __HIP_MEMORY_SCOPE_AGENT);
        *(uint32_t*)(htile[0] + wid * 2064 + colI * 2) = u0 | (u1 << 16);
    }

    // --- poll indices: 7 remote blocks x 2 words; batch row = wid
    const int pb  = wid;
    const int pc0 = lane * 2;
    int ridx[7];
    #pragma unroll
    for (int r = 0; r < 7; ++r) {
        const int rbk = (nb + 1 + r) & 7;
        ridx[r] = (gb0 + pb) * 1024 + rbk * 128 + pc0;
    }

    // --- xp preload for t=0 (all lanes; lanes>=32 mirror lanes<32)
    float xpv[4];
    #pragma unroll
    for (int i = 0; i < 4; ++i)
        xpv[i] = out[((size_t)(gb0 + r4b + i) * 512 + 0) * 1024 + col];

    for (int t = 0; t < 512; ++t) {
        const int cur = t & 1;
        uint32_t* const src = hbuf + cur * 65536;
        uint32_t* const dst = hbuf + (cur ^ 1) * 65536;
        const uint32_t exptag = (uint32_t)(t + 1);
        const uint32_t ntag   = exptag + 1;

        // --- phase A: poll the 7 remote slices; first round reads all 14,
        // retry rounds reload ONLY still-missing words (masked, parallel).
        uint32_t v[14];
        {
            #pragma unroll
            for (int r = 0; r < 7; ++r) {
                v[2 * r]     = __hip_atomic_load(&src[ridx[r]],     __ATOMIC_RELAXED, __HIP_MEMORY_SCOPE_AGENT);
                v[2 * r + 1] = __hip_atomic_load(&src[ridx[r] + 1], __ATOMIC_RELAXED, __HIP_MEMORY_SCOPE_AGENT);
            }
            int rounds = 0;
            while (true) {
                bool ok = true;
                #pragma unroll
                for (int p = 0; p < 14; ++p) ok &= ((v[p] & 0xFFFFu) == exptag);
                if (ok) break;
                #pragma unroll
                for (int p = 0; p < 14; ++p) {
                    if ((v[p] & 0xFFFFu) != exptag)
                        v[p] = __hip_atomic_load(&src[ridx[p >> 1] + (p & 1)],
                                                 __ATOMIC_RELAXED, __HIP_MEMORY_SCOPE_AGENT);
                }
                if (++rounds > 256) __builtin_amdgcn_s_sleep(2);   // paranoia only
            }
        }
        // stage remote h into this parity's LDS tile (stride-2064 rows)
        #pragma unroll
        for (int r = 0; r < 7; ++r) {
            const int rbk = (nb + 1 + r) & 7;
            const int c0  = rbk * 128 + pc0;
            const uint32_t pk = (v[2 * r] >> 16) | (v[2 * r + 1] & 0xFFFF0000u);
            *(uint32_t*)(htile[cur] + pb * 2064 + c0 * 2) = pk;
        }
        __syncthreads();   // htile[cur] complete (remote staged + own from t-1)

        // --- xp prefetch for NEXT step (off the poll's critical path)
        float xnext[4];
        if (t < 511) {
            #pragma unroll
            for (int i = 0; i < 4; ++i)
                xnext[i] = out[((size_t)(gb0 + r4b + i) * 512 + (t + 1)) * 1024 + col];
        }

        // --- phase B: acc = h . Wh[col]^T over full K, 4 interleaved chains
        f32x4 a0 = (f32x4){0.f,0.f,0.f,0.f}, a1 = a0, a2 = a0, a3 = a0;
        {
            const int b_  = lane & 7;
            const int kbx = (lane >> 4) << 4;
            const uint8_t* hb = htile[cur] + b_ * 2064;
            #pragma unroll
            for (int kt = 0; kt < 32; kt += 4) {
                const bf16x8 f0 = *(const bf16x8*)(hb + (kt    ) * 64 + kbx);
                const bf16x8 f1 = *(const bf16x8*)(hb + (kt + 1) * 64 + kbx);
                const bf16x8 f2 = *(const bf16x8*)(hb + (kt + 2) * 64 + kbx);
                const bf16x8 f3 = *(const bf16x8*)(hb + (kt + 3) * 64 + kbx);
                a0 = __builtin_amdgcn_mfma_f32_16x16x32_bf16(f0, whf[kt    ], a0, 0, 0, 0);
                a1 = __builtin_amdgcn_mfma_f32_16x16x32_bf16(f1, whf[kt + 1], a1, 0, 0, 0);
                a2 = __builtin_amdgcn_mfma_f32_16x16x32_bf16(f2, whf[kt + 2], a2, 0, 0, 0);
                a3 = __builtin_amdgcn_mfma_f32_16x16x32_bf16(f3, whf[kt + 3], a3, 0, 0, 0);
            }
        }

        // --- phase C: lanes<32 publish h (critical path); lanes>=32 (which
        // hold a duplicate C fragment) write out[] concurrently.
        float pre[4], hn[4];
        #pragma unroll
        for (int i = 0; i < 4; ++i) {
            pre[i] = ((a0[i] + a1[i]) + (a2[i] + a3[i])) + xpv[i];
            hn[i]  = fast_tanh(pre[i]);
        }
        if (lane < 32) {
            if (t < 511) {
                uint32_t hu[4];
                #pragma unroll
                for (int i = 0; i < 4; ++i) hu[i] = f2bf(hn[i]);
                #pragma unroll
                for (int i = 0; i < 4; ++i)
                    __hip_atomic_store(&dst[(gb0 + r4b + i) * 1024 + col], (hu[i] << 16) | ntag,
                                       __ATOMIC_RELAXED, __HIP_MEMORY_SCOPE_AGENT);
                // own slice -> next parity's LDS tile (never crosses global)
                #pragma unroll
                for (int i = 0; i < 4; ++i)
                    *(uint16_t*)(htile[cur ^ 1] + (r4b + i) * 2064 + col * 2) = (uint16_t)hu[i];
            }
        } else {
            #pragma unroll
            for (int i = 0; i < 4; ++i) {
                out[((size_t)(gb0 + r4b + i) * 512 + t) * 1024 + col] = pre[i];
                if (t == 511) hfin[(size_t)(gb0 + r4b + i) * 1024 + col] = hn[i];
            }
        }
        #pragma unroll
        for (int i = 0; i < 4; ++i) xpv[i] = xnext[i];
    }
}

// ---------------------------------------------------------------------------
extern "C" void kernel_launch(void* const* d_in, const int* in_sizes, int n_in,
                              void* d_out, int out_size, void* d_ws, size_t ws_size,
                              hipStream_t stream) {
    const float* x   = (const float*)d_in[0];   // [64,512,512]
    const float* h0_ = (const float*)d_in[1];   // [64,1024]
    const float* Wx  = (const float*)d_in[2];   // [1024,512]
    const float* bx  = (const float*)d_in[3];   // [1024]
    const float* Wh  = (const float*)d_in[4];   // [1024,1024]
    const float* bh  = (const float*)d_in[5];   // [1024]
    float* out  = (float*)d_out;                         // [64,512,1024] pre
    float* hfin = out + (size_t)64 * 512 * 1024;         // [64,1024]
    uint32_t* hbuf = (uint32_t*)d_ws;                    // [2][64][1024] u32 = 512 KB

    // invalidate all tags (0xFFFF matches no step tag 1..513)
    hipMemsetAsync(d_ws, 0xFF, (size_t)2 * 64 * 1024 * sizeof(uint32_t), stream);

    xproj_gemm<<<dim3(2048), dim3(256), 0, stream>>>(x, Wx, bx, bh, out);
    rnn_scan<<<dim3(64), dim3(512), 0, stream>>>(h0_, Wh, out, hfin, hbuf);
}

// Round 14
// 1320.226 us; speedup vs baseline: 1.7081x; 1.4722x over previous
//
#include <hip/hip_runtime.h>
#include <stdint.h>

// MyVanillaRNN: B=64, T=512, INPUT=512, HIDDEN=1024
// out = concat( pre[B,T,H] (f32), h_final[B,H] (f32) )

typedef __attribute__((ext_vector_type(8))) short bf16x8;
typedef __attribute__((ext_vector_type(4))) float f32x4;
typedef unsigned long long u64;

__device__ __forceinline__ uint32_t f2bf(float f) {
    union { float f; uint32_t u; } v; v.f = f;
    return (v.u + 0x7FFFu + ((v.u >> 16) & 1u)) >> 16;   // RNE
}
__device__ __forceinline__ uint32_t pack2bf(float a, float b) {
    return f2bf(a) | (f2bf(b) << 16);
}
__device__ __forceinline__ float fast_tanh(float x) {
    const float xc = fminf(fmaxf(x, -15.f), 15.f);
    const float e  = __expf(2.f * xc);
    return (e - 1.f) * __builtin_amdgcn_rcpf(e + 1.f);
}

// ---------------------------------------------------------------------------
// Phase 1: out[m][n] = sum_k x[m][k]*Wx[n][k] + bx[n] + bh[n]
// M=32768, N=1024, K=512.  128x128 tile, BK=64, 4 waves, bf16 MFMA.
// ---------------------------------------------------------------------------
__global__ __launch_bounds__(256) void xproj_gemm(
    const float* __restrict__ x, const float* __restrict__ Wx,
    const float* __restrict__ bx, const float* __restrict__ bh,
    float* __restrict__ out)
{
    __shared__ __align__(16) uint8_t Ab[128 * 128];
    __shared__ __align__(16) uint8_t Bb[128 * 128];

    const int tid  = threadIdx.x;
    const int lane = tid & 63;
    const int wid  = tid >> 6;
    const int wm = wid >> 1, wn = wid & 1;
    const int m0 = (int)(blockIdx.x >> 3) * 128;
    const int n0 = (int)(blockIdx.x & 7) * 128;

    f32x4 acc[4][4];
    #pragma unroll
    for (int i = 0; i < 4; ++i)
        #pragma unroll
        for (int j = 0; j < 4; ++j) acc[i][j] = (f32x4){0.f, 0.f, 0.f, 0.f};

    const int sr = tid >> 4;
    const int sk = (tid & 15) << 2;

    for (int k0 = 0; k0 < 512; k0 += 64) {
        __syncthreads();
        #pragma unroll
        for (int p = 0; p < 8; ++p) {
            const int r = sr + p * 16;
            const float4 a = *(const float4*)(x  + (size_t)(m0 + r) * 512 + k0 + sk);
            const float4 b = *(const float4*)(Wx + (size_t)(n0 + r) * 512 + k0 + sk);
            const int byo = r * 128 + ((sk << 1) ^ ((r & 7) << 4));
            *(uint2*)(Ab + byo) = make_uint2(pack2bf(a.x, a.y), pack2bf(a.z, a.w));
            *(uint2*)(Bb + byo) = make_uint2(pack2bf(b.x, b.y), pack2bf(b.z, b.w));
        }
        __syncthreads();
        #pragma unroll
        for (int kt = 0; kt < 2; ++kt) {
            bf16x8 af[4], bfr[4];
            const int kb = (kt << 6) + ((lane >> 4) << 4);
            #pragma unroll
            for (int q = 0; q < 4; ++q) {
                const int ar = wm * 64 + q * 16 + (lane & 15);
                const int br = wn * 64 + q * 16 + (lane & 15);
                af[q]  = *(const bf16x8*)(Ab + ar * 128 + (kb ^ ((ar & 7) << 4)));
                bfr[q] = *(const bf16x8*)(Bb + br * 128 + (kb ^ ((br & 7) << 4)));
            }
            #pragma unroll
            for (int mt = 0; mt < 4; ++mt)
                #pragma unroll
                for (int nt = 0; nt < 4; ++nt)
                    acc[mt][nt] = __builtin_amdgcn_mfma_f32_16x16x32_bf16(
                        af[mt], bfr[nt], acc[mt][nt], 0, 0, 0);
        }
    }

    #pragma unroll
    for (int nt = 0; nt < 4; ++nt) {
        const int n = n0 + wn * 64 + nt * 16 + (lane & 15);
        const float bias = bx[n] + bh[n];
        #pragma unroll
        for (int mt = 0; mt < 4; ++mt) {
            const int mb = m0 + wm * 64 + mt * 16 + ((lane >> 4) << 2);
            #pragma unroll
            for (int i = 0; i < 4; ++i)
                out[(size_t)(mb + i) * 1024 + n] = acc[mt][nt][i] + bias;
        }
    }
}

// ---------------------------------------------------------------------------
// Phase 2: persistent scan. 8 groups (8 batches) x 8 blocks (128 H-cols).
// EXACT round-11 structure (best verified: 1443us) with ONE change:
//   u64 POLL LOADS: each thread's 2 adjacent tag words per chunk load as
//   ONE 8B agent-scope atomic (global_load_dwordx2) -> 7 loads/thread vs
//   14, halving chip-wide poll transactions (~229K vs 459K per round).
//   Each 32-bit half is still tag-checked independently (no widened
//   atomicity assumption). Flat parallel re-poll every round (r13's masked
//   version regressed: divergent per-word guards serialize).
//   De-confounds r8: its u64 regression bundled the pipelined double-issue
//   poll that r12 isolated at -50%.
// h exchange: tagged words (bf16(h)<<16 | (t+1)); relaxed agent-scope
// atomics only (r3/5/7: L2-local paths never deliver fresh data; r9:
// ACK+tag 2-hop serializes; r10: asm streaming poll compiler-unsafe).
// htile row stride 2064B. Own cols never cross global (parity LDS dbuf).
// xp software-pipelined one step ahead. LDS padded >80KB -> 1 block/CU.
// ---------------------------------------------------------------------------
__global__ __launch_bounds__(512, 1) void rnn_scan(
    const float* __restrict__ h0, const float* __restrict__ Wh,
    float* __restrict__ out, float* __restrict__ hfin,
    uint32_t* __restrict__ hbuf)   // [2][64][1024] tagged words
{
    // rows 0..7 (x2064B) per parity used; rest pads LDS > 80KB => 1 block/CU.
    __shared__ __align__(16) uint8_t htile[2][49152];

    const int tid  = threadIdx.x;
    const int lane = tid & 63;
    const int wid  = tid >> 6;          // 0..7
    const int g    = (int)blockIdx.x & 7;
    const int nb   = (int)blockIdx.x >> 3;
    const int gb0  = g * 8;             // batch base
    const int col  = nb * 128 + wid * 16 + (lane & 15);   // own output col
    const int r4b  = ((lane >> 4) & 1) << 2;              // 0/4 batch sub-base

    // --- Wh B-fragments: own col, full K. frag kt elem j <-> k=kt*32+(lane>>4)*8+j
    bf16x8 whf[32];
    {
        const float* wp = Wh + (size_t)col * 1024 + ((lane >> 4) << 3);
        #pragma unroll
        for (int kt = 0; kt < 32; ++kt) {
            const float4 w0 = *(const float4*)(wp + kt * 32);
            const float4 w1 = *(const float4*)(wp + kt * 32 + 4);
            bf16x8 f;
            f[0] = (short)f2bf(w0.x); f[1] = (short)f2bf(w0.y);
            f[2] = (short)f2bf(w0.z); f[3] = (short)f2bf(w0.w);
            f[4] = (short)f2bf(w1.x); f[5] = (short)f2bf(w1.y);
            f[6] = (short)f2bf(w1.z); f[7] = (short)f2bf(w1.w);
            whf[kt] = f;
        }
    }

    // --- init: publish own slice of h0 (tag 1, parity 0) + own LDS fill
    {
        const int colI = nb * 128 + lane * 2;   // two adjacent own cols
        const uint32_t u0 = f2bf(h0[(size_t)(gb0 + wid) * 1024 + colI]);
        const uint32_t u1 = f2bf(h0[(size_t)(gb0 + wid) * 1024 + colI + 1]);
        const int idx = (gb0 + wid) * 1024 + colI;
        __hip_atomic_store(&hbuf[idx],     (u0 << 16) | 1u, __ATOMIC_RELAXED, __HIP_MEMORY_SCOPE_AGENT);
        __hip_atomic_store(&hbuf[idx + 1], (u1 << 16) | 1u, __ATOMIC_RELAXED, __HIP_MEMORY_SCOPE_AGENT);
        *(uint32_t*)(htile[0] + wid * 2064 + colI * 2) = u0 | (u1 << 16);
    }

    // --- poll indices: 7 remote blocks x 1 u64 (2 words); batch row = wid
    const int pb  = wid;
    const int pc0 = lane * 2;
    int ridx[7];
    #pragma unroll
    for (int r = 0; r < 7; ++r) {
        const int rbk = (nb + 1 + r) & 7;
        ridx[r] = (gb0 + pb) * 1024 + rbk * 128 + pc0;   // even -> 8B aligned
    }

    // --- xp preload for t=0 (all lanes; lanes>=32 mirror lanes<32)
    float xpv[4];
    #pragma unroll
    for (int i = 0; i < 4; ++i)
        xpv[i] = out[((size_t)(gb0 + r4b + i) * 512 + 0) * 1024 + col];

    for (int t = 0; t < 512; ++t) {
        const int cur = t & 1;
        uint32_t* const src = hbuf + cur * 65536;
        uint32_t* const dst = hbuf + (cur ^ 1) * 65536;
        const uint32_t exptag = (uint32_t)(t + 1);
        const uint32_t ntag   = exptag + 1;
        const u64 tag2 = ((u64)exptag << 32) | (u64)exptag;

        // --- phase A: poll the 7 remote slices (7x u64 agent loads, tight)
        u64 w[7];
        int rounds = 0;
        while (true) {
            #pragma unroll
            for (int r = 0; r < 7; ++r)
                w[r] = __hip_atomic_load((const u64*)&src[ridx[r]],
                                         __ATOMIC_RELAXED, __HIP_MEMORY_SCOPE_AGENT);
            bool ok = true;
            #pragma unroll
            for (int r = 0; r < 7; ++r)
                ok &= (((w[r] ^ tag2) & 0x0000FFFF0000FFFFull) == 0);
            if (ok) break;
            if (++rounds > 256) __builtin_amdgcn_s_sleep(2);   // paranoia only
        }
        // stage remote h into this parity's LDS tile (stride-2064 rows)
        #pragma unroll
        for (int r = 0; r < 7; ++r) {
            const int rbk = (nb + 1 + r) & 7;
            const int c0  = rbk * 128 + pc0;
            const uint32_t lo = (uint32_t)w[r];
            const uint32_t hi = (uint32_t)(w[r] >> 32);
            const uint32_t pk = (lo >> 16) | (hi & 0xFFFF0000u);
            *(uint32_t*)(htile[cur] + pb * 2064 + c0 * 2) = pk;
        }
        __syncthreads();   // htile[cur] complete (remote staged + own from t-1)

        // --- xp prefetch for NEXT step (off the poll's critical path)
        float xnext[4];
        if (t < 511) {
            #pragma unroll
            for (int i = 0; i < 4; ++i)
                xnext[i] = out[((size_t)(gb0 + r4b + i) * 512 + (t + 1)) * 1024 + col];
        }

        // --- phase B: acc = h . Wh[col]^T over full K, 4 interleaved chains
        f32x4 a0 = (f32x4){0.f,0.f,0.f,0.f}, a1 = a0, a2 = a0, a3 = a0;
        {
            const int b_  = lane & 7;
            const int kbx = (lane >> 4) << 4;
            const uint8_t* hb = htile[cur] + b_ * 2064;
            #pragma unroll
            for (int kt = 0; kt < 32; kt += 4) {
                const bf16x8 f0 = *(const bf16x8*)(hb + (kt    ) * 64 + kbx);
                const bf16x8 f1 = *(const bf16x8*)(hb + (kt + 1) * 64 + kbx);
                const bf16x8 f2 = *(const bf16x8*)(hb + (kt + 2) * 64 + kbx);
                const bf16x8 f3 = *(const bf16x8*)(hb + (kt + 3) * 64 + kbx);
                a0 = __builtin_amdgcn_mfma_f32_16x16x32_bf16(f0, whf[kt    ], a0, 0, 0, 0);
                a1 = __builtin_amdgcn_mfma_f32_16x16x32_bf16(f1, whf[kt + 1], a1, 0, 0, 0);
                a2 = __builtin_amdgcn_mfma_f32_16x16x32_bf16(f2, whf[kt + 2], a2, 0, 0, 0);
                a3 = __builtin_amdgcn_mfma_f32_16x16x32_bf16(f3, whf[kt + 3], a3, 0, 0, 0);
            }
        }

        // --- phase C: lanes<32 publish h (critical path); lanes>=32 (which
        // hold a duplicate C fragment) write out[] concurrently.
        float pre[4], hn[4];
        #pragma unroll
        for (int i = 0; i < 4; ++i) {
            pre[i] = ((a0[i] + a1[i]) + (a2[i] + a3[i])) + xpv[i];
            hn[i]  = fast_tanh(pre[i]);
        }
        if (lane < 32) {
            if (t < 511) {
                uint32_t hu[4];
                #pragma unroll
                for (int i = 0; i < 4; ++i) hu[i] = f2bf(hn[i]);
                #pragma unroll
                for (int i = 0; i < 4; ++i)
                    __hip_atomic_store(&dst[(gb0 + r4b + i) * 1024 + col], (hu[i] << 16) | ntag,
                                       __ATOMIC_RELAXED, __HIP_MEMORY_SCOPE_AGENT);
                // own slice -> next parity's LDS tile (never crosses global)
                #pragma unroll
                for (int i = 0; i < 4; ++i)
                    *(uint16_t*)(htile[cur ^ 1] + (r4b + i) * 2064 + col * 2) = (uint16_t)hu[i];
            }
        } else {
            #pragma unroll
            for (int i = 0; i < 4; ++i) {
                out[((size_t)(gb0 + r4b + i) * 512 + t) * 1024 + col] = pre[i];
                if (t == 511) hfin[(size_t)(gb0 + r4b + i) * 1024 + col] = hn[i];
            }
        }
        #pragma unroll
        for (int i = 0; i < 4; ++i) xpv[i] = xnext[i];
    }
}

// ---------------------------------------------------------------------------
extern "C" void kernel_launch(void* const* d_in, const int* in_sizes, int n_in,
                              void* d_out, int out_size, void* d_ws, size_t ws_size,
                              hipStream_t stream) {
    const float* x   = (const float*)d_in[0];   // [64,512,512]
    const float* h0_ = (const float*)d_in[1];   // [64,1024]
    const float* Wx  = (const float*)d_in[2];   // [1024,512]
    const float* bx  = (const float*)d_in[3];   // [1024]
    const float* Wh  = (const float*)d_in[4];   // [1024,1024]
    const float* bh  = (const float*)d_in[5];   // [1024]
    float* out  = (float*)d_out;                         // [64,512,1024] pre
    float* hfin = out + (size_t)64 * 512 * 1024;         // [64,1024]
    uint32_t* hbuf = (uint32_t*)d_ws;                    // [2][64][1024] u32 = 512 KB

    // invalidate all tags (0xFFFF matches no step tag 1..513)
    hipMemsetAsync(d_ws, 0xFF, (size_t)2 * 64 * 1024 * sizeof(uint32_t), stream);

    xproj_gemm<<<dim3(2048), dim3(256), 0, stream>>>(x, Wx, bx, bh, out);
    rnn_scan<<<dim3(64), dim3(512), 0, stream>>>(h0_, Wh, out, hfin, hbuf);
}